// Round 9
// baseline (114.785 us; speedup 1.0000x reference)
//
#include <hip/hip_runtime.h>

#define IMG 512
#define BATCH 64
#define RPS 32          // output rows per strip
#define NSTEP 42        // RPS + 10 halo rows

typedef float v2f __attribute__((ext_vector_type(2)));

__device__ __forceinline__ float bperm(int addr, float v) {
    return __int_as_float(__builtin_amdgcn_ds_bpermute(addr, __float_as_int(v)));
}
__device__ __forceinline__ v2f bperm2(int addr, v2f v) {
    v2f r; r.x = bperm(addr, v.x); r.y = bperm(addr, v.y); return r;
}

__global__ __launch_bounds__(256, 2) void ssim_shfl_kernel(
    const float* __restrict__ img1, const float* __restrict__ img2,
    const float* __restrict__ window, float* __restrict__ partials)
{
    __shared__ float wred[4];

    const int tid   = threadIdx.x;
    const int lane  = tid & 63;
    const int wv    = tid >> 6;          // wave 0..3
    const int strip = blockIdx.x;        // 0..15
    const int b     = blockIdx.y;        // batch
    const int r_base = strip * RPS;
    const int c0    = wv * 128 + lane * 2;   // own cols c0, c0+1 (0..510)

    // 1-D gaussian = row sums of the 11x11 window; force to SGPR
    float gw[11];
    #pragma unroll
    for (int k = 0; k < 11; ++k) {
        float s = 0.f;
        #pragma unroll
        for (int j = 0; j < 11; ++j) s += window[k*11 + j];
        gw[k] = __int_as_float(__builtin_amdgcn_readfirstlane(__float_as_int(s)));
    }

    const float* P1 = img1 + (size_t)b * (IMG*IMG);
    const float* P2 = img2 + (size_t)b * (IMG*IMG);

    const bool ledge = (lane < 3);
    const bool redge = (lane > 60);

    // bpermute lane addresses for shifts -3..-1, +1..+3
    int adr_m[3], adr_p[3];
    #pragma unroll
    for (int d = 1; d <= 3; ++d) { adr_m[d-1] = (lane - d) << 2; adr_p[d-1] = (lane + d) << 2; }

    // own-pair loader (next-row prefetch target)
    auto load_own = [&](int rr, v2f& o1, v2f& o2) {
        o1 = (v2f){0.f,0.f}; o2 = (v2f){0.f,0.f};
        if (rr >= 0 && rr < IMG) {
            o1 = *(const v2f*)(P1 + (size_t)rr*IMG + c0);
            o2 = *(const v2f*)(P2 + (size_t)rr*IMG + c0);
        }
    };

    v2f cur1, cur2;
    load_own(r_base - 5, cur1, cur2);

    // 11-slot ring of vertical accumulators: 5 channels, col-pair packed
    v2f acc[11][5];
    #pragma unroll
    for (int s = 0; s < 11; ++s)
        #pragma unroll
        for (int ch = 0; ch < 5; ++ch) acc[s][ch] = (v2f){0.f, 0.f};

    v2f rsum = (v2f){0.f, 0.f};
    const float C1 = 1e-4f, C2 = 9e-4f;

    #pragma unroll 1
    for (int jj = 0; jj < 4; ++jj) {
      #pragma unroll
      for (int u = 0; u < 11; ++u) {
        const int t = jj*11 + u;               // t mod 11 == u (compile-time ring slots)
        if (t < NSTEP) {
          const int rr = r_base - 5 + t;
          const bool rowok = (rr >= 0) && (rr < IMG);

          // (1) prefetch next row's own pair (hidden under this step's compute)
          v2f nxt1, nxt2;
          load_own(rr + 1, nxt1, nxt2);        // rr+1==NSTEP case loads a valid row; unused next iter of last step — harmless

          // (2) edge-halo direct loads (only 6 lanes per wave take these)
          v2f el1[3], el2[3], er1[3], er2[3];
          #pragma unroll
          for (int i = 0; i < 3; ++i) {
            el1[i]=(v2f){0.f,0.f}; el2[i]=(v2f){0.f,0.f};
            er1[i]=(v2f){0.f,0.f}; er2[i]=(v2f){0.f,0.f};
          }
          if (rowok && ledge) {
            const float* r1 = P1 + (size_t)rr*IMG;
            const float* r2 = P2 + (size_t)rr*IMG;
            #pragma unroll
            for (int i = 0; i < 3; ++i) {
              int cc = c0 - 6 + 2*i;
              if (cc >= 0) { el1[i] = *(const v2f*)(r1 + cc); el2[i] = *(const v2f*)(r2 + cc); }
            }
          }
          if (rowok && redge) {
            const float* r1 = P1 + (size_t)rr*IMG;
            const float* r2 = P2 + (size_t)rr*IMG;
            #pragma unroll
            for (int i = 0; i < 3; ++i) {
              int cc = c0 + 2 + 2*i;
              if (cc <= IMG-2) { er1[i] = *(const v2f*)(r1 + cc); er2[i] = *(const v2f*)(r2 + cc); }
            }
          }

          // (3) build 14-col windows via intra-wave bpermute; L[q]=(a[2q],a[2q+1]), a[e]=col c0-6+e
          v2f L1[7], L2[7];
          L1[3] = cur1;                 L2[3] = cur2;
          L1[2] = bperm2(adr_m[0], cur1); L2[2] = bperm2(adr_m[0], cur2);
          L1[1] = bperm2(adr_m[1], cur1); L2[1] = bperm2(adr_m[1], cur2);
          L1[0] = bperm2(adr_m[2], cur1); L2[0] = bperm2(adr_m[2], cur2);
          L1[4] = bperm2(adr_p[0], cur1); L2[4] = bperm2(adr_p[0], cur2);
          L1[5] = bperm2(adr_p[1], cur1); L2[5] = bperm2(adr_p[1], cur2);
          L1[6] = bperm2(adr_p[2], cur1); L2[6] = bperm2(adr_p[2], cur2);
          if (ledge) {
            #pragma unroll
            for (int i = 0; i < 3; ++i) { L1[i] = el1[i]; L2[i] = el2[i]; }
          }
          if (redge) {
            #pragma unroll
            for (int i = 0; i < 3; ++i) { L1[4+i] = er1[i]; L2[4+i] = er2[i]; }
          }

          // (4) packed horizontal conv: pair (a[k+1],a[k+2]) feeds both cols at once
          v2f h1 = (v2f){0,0}, h2 = (v2f){0,0};
          v2f h11 = (v2f){0,0}, h22 = (v2f){0,0}, h12 = (v2f){0,0};
          #pragma unroll
          for (int k = 0; k < 11; ++k) {
            v2f pa, pb;
            if (k & 1) {                       // k odd: natural pair L[(k+1)/2]
              pa = L1[(k+1) >> 1]; pb = L2[(k+1) >> 1];
            } else {                           // k even: straddling pair
              pa = __builtin_shufflevector(L1[k>>1], L1[(k>>1)+1], 1, 2);
              pb = __builtin_shufflevector(L2[k>>1], L2[(k>>1)+1], 1, 2);
            }
            float w = gw[k];
            h1  += w * pa;
            h2  += w * pb;
            h11 += w * (pa * pa);
            h22 += w * (pb * pb);
            h12 += w * (pa * pb);
          }

          // (5) packed vertical ring accumulate: slot s takes tap k = 10 - ((s-u) mod 11)
          #pragma unroll
          for (int s = 0; s < 11; ++s) {
            const int k = 10 - (((s - u) % 11 + 11) % 11);
            const float w = gw[k];
            acc[s][0] += w * h1;
            acc[s][1] += w * h2;
            acc[s][2] += w * h11;
            acc[s][3] += w * h22;
            acc[s][4] += w * h12;
          }

          // (6) slot u completed its 11 taps (out-row r_base - 10 + t)
          if (t >= 10) {
            v2f mu1 = acc[u][0], mu2 = acc[u][1];
            v2f mu1s = mu1*mu1, mu2s = mu2*mu2, mu12 = mu1*mu2;
            v2f s1  = acc[u][2] - mu1s;
            v2f s2  = acc[u][3] - mu2s;
            v2f s12 = acc[u][4] - mu12;
            v2f num = (2.f*mu12 + C1) * (2.f*s12 + C2);
            v2f den = (mu1s + mu2s + C1) * (s1 + s2 + C2);
            v2f r;
            r.x = num.x * __builtin_amdgcn_rcpf(den.x);
            r.y = num.y * __builtin_amdgcn_rcpf(den.y);
            rsum += r;
          }
          #pragma unroll
          for (int ch = 0; ch < 5; ++ch) acc[u][ch] = (v2f){0.f, 0.f};

          cur1 = nxt1; cur2 = nxt2;
        }
      }
    }

    float thr_sum = rsum.x + rsum.y;

    // block reduction (single barrier, after the loop)
    for (int d = 32; d > 0; d >>= 1) thr_sum += __shfl_down(thr_sum, d, 64);
    if ((tid & 63) == 0) wred[wv] = thr_sum;
    __syncthreads();
    if (tid == 0) {
        float s = wred[0] + wred[1] + wred[2] + wred[3];
        partials[blockIdx.y * 16 + blockIdx.x] = s;
    }
}

__global__ __launch_bounds__(256) void ssim_reduce_kernel(
    const float* __restrict__ partials, int n, float* __restrict__ out)
{
    __shared__ double wsumd[4];
    double s = 0.0;
    for (int i = threadIdx.x; i < n; i += 256) s += (double)partials[i];
    for (int d = 32; d > 0; d >>= 1) s += __shfl_down(s, d, 64);
    int wid = threadIdx.x >> 6, lane = threadIdx.x & 63;
    if (lane == 0) wsumd[wid] = s;
    __syncthreads();
    if (threadIdx.x == 0) {
        double t = wsumd[0] + wsumd[1] + wsumd[2] + wsumd[3];
        out[0] = (float)(t / ((double)BATCH * IMG * IMG));
    }
}

extern "C" void kernel_launch(void* const* d_in, const int* in_sizes, int n_in,
                              void* d_out, int out_size, void* d_ws, size_t ws_size,
                              hipStream_t stream) {
    const float* img1   = (const float*)d_in[0];
    const float* img2   = (const float*)d_in[1];
    const float* window = (const float*)d_in[2];
    float* out = (float*)d_out;
    float* partials = (float*)d_ws;

    dim3 grid(IMG / RPS, BATCH);   // 16 x 64 = 1024 blocks
    ssim_shfl_kernel<<<grid, dim3(256), 0, stream>>>(img1, img2, window, partials);

    int npart = (IMG / RPS) * BATCH;  // 1024
    ssim_reduce_kernel<<<1, 256, 0, stream>>>(partials, npart, out);
}

// Round 10
// 80.680 us; speedup vs baseline: 1.4227x; 1.4227x over previous
//
#include <hip/hip_runtime.h>

#define IMG 512
#define BATCH 64
#define RPS 32          // output rows per strip
#define NSTEP 42        // RPS + 10 halo rows
#define WPW 144         // words per wave-row buffer: 140 used (cols cbase-6 .. cbase+133) + pad

typedef float v2f __attribute__((ext_vector_type(2)));

__global__ __launch_bounds__(256, 2) void ssim_wavering_kernel(
    const float* __restrict__ img1, const float* __restrict__ img2,
    const float* __restrict__ window, float* __restrict__ partials)
{
    __shared__ float S[4][2][2][WPW];    // [wave][buf][img][word]  9216 B
    __shared__ float wred[4];

    const int tid   = threadIdx.x;
    const int lane  = tid & 63;
    const int wv    = tid >> 6;          // wave 0..3
    const int strip = blockIdx.x;        // 0..15
    const int b     = blockIdx.y;        // batch
    const int r_base = strip * RPS;
    const int cbase = wv * 128;          // wave's first output col
    const int c0    = cbase + lane * 2;  // own cols c0, c0+1

    // 1-D gaussian = row sums of the 11x11 window; force to SGPR
    float gw[11];
    #pragma unroll
    for (int k = 0; k < 11; ++k) {
        float s = 0.f;
        #pragma unroll
        for (int j = 0; j < 11; ++j) s += window[k*11 + j];
        gw[k] = __int_as_float(__builtin_amdgcn_readfirstlane(__float_as_int(s)));
    }

    const float* P1 = img1 + (size_t)b * (IMG*IMG);
    const float* P2 = img2 + (size_t)b * (IMG*IMG);

    // halo duty: 3 left lanes + 3 right lanes per wave
    const bool lh = (lane < 3);                  // words 2*lane .. 2*lane+1   (cols cbase-6+2*lane)
    const bool rh = (lane >= 61);                // words 134+2*(lane-61) ..   (cols cbase+128+2*(lane-61))
    const int  lcol = cbase - 6 + 2*lane;
    const int  rcol = cbase + 128 + 2*(lane - 61);
    const bool lok = lh && (lcol >= 0);
    const bool rok = rh && (rcol <= IMG-2);

    // fetch row rr: own pair + (for duty lanes) halo pair. Zeros when OOB.
    auto fetch = [&](int rr, v2f& o1, v2f& o2, v2f& h1_, v2f& h2_) {
        o1=(v2f){0,0}; o2=(v2f){0,0}; h1_=(v2f){0,0}; h2_=(v2f){0,0};
        if (rr >= 0 && rr < IMG) {
            const float* q1 = P1 + (size_t)rr*IMG;
            const float* q2 = P2 + (size_t)rr*IMG;
            o1 = *(const v2f*)(q1 + c0);
            o2 = *(const v2f*)(q2 + c0);
            if (lok) { h1_ = *(const v2f*)(q1 + lcol); h2_ = *(const v2f*)(q2 + lcol); }
            if (rok) { h1_ = *(const v2f*)(q1 + rcol); h2_ = *(const v2f*)(q2 + rcol); }
        }
    };
    // store into this wave's buffer `buf` (same-wave ds ops -> no barrier needed)
    auto store = [&](int buf, v2f o1, v2f o2, v2f h1_, v2f h2_) {
        *(v2f*)&S[wv][buf][0][6 + 2*lane] = o1;
        *(v2f*)&S[wv][buf][1][6 + 2*lane] = o2;
        if (lh) { *(v2f*)&S[wv][buf][0][2*lane] = h1_;
                  *(v2f*)&S[wv][buf][1][2*lane] = h2_; }
        if (rh) { *(v2f*)&S[wv][buf][0][134 + 2*(lane-61)] = h1_;
                  *(v2f*)&S[wv][buf][1][134 + 2*(lane-61)] = h2_; }
    };

    // prefill buf 0 with raw row r_base-5
    {
        v2f o1,o2,e1,e2;
        fetch(r_base - 5, o1,o2,e1,e2);
        store(0, o1,o2,e1,e2);
    }

    // 11-slot ring of vertical accumulators: 5 channels, col-pair packed
    v2f acc[11][5];
    #pragma unroll
    for (int s = 0; s < 11; ++s)
        #pragma unroll
        for (int ch = 0; ch < 5; ++ch) acc[s][ch] = (v2f){0.f, 0.f};

    v2f rsum = (v2f){0.f, 0.f};
    const float C1 = 1e-4f, C2 = 9e-4f;

    #pragma unroll 1
    for (int jj = 0; jj < 4; ++jj) {
      #pragma unroll
      for (int u = 0; u < 11; ++u) {
        const int t = jj*11 + u;               // t mod 11 == u (compile-time ring slots)
        if (t < NSTEP) {
          const int rr = r_base - 5 + t;

          // (1) global prefetch of next row (issue early, write to LDS late)
          v2f n1,n2,f1,f2;
          const bool do_stage = (t+1 < NSTEP);
          if (do_stage) fetch(rr + 1, n1,n2,f1,f2);

          // (2) read this step's 14-col window from the wave's buffer: 7 x b64 per image
          const float* R1 = &S[wv][t & 1][0][0];
          const float* R2 = &S[wv][t & 1][1][0];
          v2f L1[7], L2[7];                    // L[q] = cols c0-6+2q, c0-5+2q
          #pragma unroll
          for (int q = 0; q < 7; ++q) {
            L1[q] = *(const v2f*)&R1[2*lane + 2*q];
            L2[q] = *(const v2f*)&R2[2*lane + 2*q];
          }

          // (3) packed horizontal conv: pair (a[k+1],a[k+2]) feeds both cols at once
          v2f h1 = (v2f){0,0}, h2 = (v2f){0,0};
          v2f h11 = (v2f){0,0}, h22 = (v2f){0,0}, h12 = (v2f){0,0};
          #pragma unroll
          for (int k = 0; k < 11; ++k) {
            v2f pa, pb;
            if (k & 1) {                       // k odd: natural pair L[(k+1)/2]
              pa = L1[(k+1) >> 1]; pb = L2[(k+1) >> 1];
            } else {                           // k even: straddling pair
              pa = __builtin_shufflevector(L1[k>>1], L1[(k>>1)+1], 1, 2);
              pb = __builtin_shufflevector(L2[k>>1], L2[(k>>1)+1], 1, 2);
            }
            float w = gw[k];
            h1  += w * pa;
            h2  += w * pb;
            h11 += w * (pa * pa);
            h22 += w * (pb * pb);
            h12 += w * (pa * pb);
          }

          // (4) packed vertical ring accumulate: slot s takes tap k = 10 - ((s-u) mod 11)
          #pragma unroll
          for (int s = 0; s < 11; ++s) {
            const int k = 10 - (((s - u) % 11 + 11) % 11);
            const float w = gw[k];
            acc[s][0] += w * h1;
            acc[s][1] += w * h2;
            acc[s][2] += w * h11;
            acc[s][3] += w * h22;
            acc[s][4] += w * h12;
          }

          // (5) slot u completed its 11 taps (out-row r_base - 10 + t)
          if (t >= 10) {
            v2f mu1 = acc[u][0], mu2 = acc[u][1];
            v2f mu1s = mu1*mu1, mu2s = mu2*mu2, mu12 = mu1*mu2;
            v2f s1  = acc[u][2] - mu1s;
            v2f s2  = acc[u][3] - mu2s;
            v2f s12 = acc[u][4] - mu12;
            v2f num = (2.f*mu12 + C1) * (2.f*s12 + C2);
            v2f den = (mu1s + mu2s + C1) * (s1 + s2 + C2);
            v2f r;
            r.x = num.x * __builtin_amdgcn_rcpf(den.x);
            r.y = num.y * __builtin_amdgcn_rcpf(den.y);
            rsum += r;
          }
          #pragma unroll
          for (int ch = 0; ch < 5; ++ch) acc[u][ch] = (v2f){0.f, 0.f};

          // (6) stage next row into the other buffer (same-wave; lgkmcnt orders it)
          if (do_stage) store((t+1) & 1, n1,n2,f1,f2);
        }
      }
    }

    float thr_sum = rsum.x + rsum.y;

    // block reduction (single barrier, after the loop)
    for (int d = 32; d > 0; d >>= 1) thr_sum += __shfl_down(thr_sum, d, 64);
    if (lane == 0) wred[wv] = thr_sum;
    __syncthreads();
    if (tid == 0) {
        float s = wred[0] + wred[1] + wred[2] + wred[3];
        partials[blockIdx.y * 16 + blockIdx.x] = s;
    }
}

__global__ __launch_bounds__(256) void ssim_reduce_kernel(
    const float* __restrict__ partials, int n, float* __restrict__ out)
{
    __shared__ double wsumd[4];
    double s = 0.0;
    for (int i = threadIdx.x; i < n; i += 256) s += (double)partials[i];
    for (int d = 32; d > 0; d >>= 1) s += __shfl_down(s, d, 64);
    int wid = threadIdx.x >> 6, lane = threadIdx.x & 63;
    if (lane == 0) wsumd[wid] = s;
    __syncthreads();
    if (threadIdx.x == 0) {
        double t = wsumd[0] + wsumd[1] + wsumd[2] + wsumd[3];
        out[0] = (float)(t / ((double)BATCH * IMG * IMG));
    }
}

extern "C" void kernel_launch(void* const* d_in, const int* in_sizes, int n_in,
                              void* d_out, int out_size, void* d_ws, size_t ws_size,
                              hipStream_t stream) {
    const float* img1   = (const float*)d_in[0];
    const float* img2   = (const float*)d_in[1];
    const float* window = (const float*)d_in[2];
    float* out = (float*)d_out;
    float* partials = (float*)d_ws;

    dim3 grid(IMG / RPS, BATCH);   // 16 x 64 = 1024 blocks
    ssim_wavering_kernel<<<grid, dim3(256), 0, stream>>>(img1, img2, window, partials);

    int npart = (IMG / RPS) * BATCH;  // 1024
    ssim_reduce_kernel<<<1, 256, 0, stream>>>(partials, npart, out);
}